// Round 3
// baseline (92.420 us; speedup 1.0000x reference)
//
#include <hip/hip_runtime.h>

// Performer causal linear attention — 3-dispatch bf16-MFMA pipeline, L=64.
// B=4, S=2048, D=128; chunks of L=64 (128 chunks, 32/batch).
//  phikv (256 blk x 512 thr): phi = scale*exp(W@x) via MFMA; phi stored to
//         global DIRECTLY from acc regs; K-blocks also emit per-chunk
//         KVT[e][d] (bf16, [b][e][c][d]) + N[d] (fp32, 512-thr spread).
//  scan  (132 blk x 64 thr): exclusive chunk-prefix of KVT -> Mpre
//         (bf16 [b][c][e][d], fp32-accumulated) and N32 -> Npre (fp32).
//  out (512 blk x 512 thr, 2 blk/CU = 16 waves/CU): Mpre/Npre direct loads,
//         P=QK^T (8 waves x 2 tiles, balanced, zero-tiles written),
//         out = P@V + Q@M (1 combo/wave); fp32 denominators (8 lanes/row).
// (R5: grid barriers ~100us across non-coherent XCD L2s.  R10: scan
//  dispatch removed out's O(c) prefix, -4.3us.  R11: latency shaves -1.4us.
//  This round: out_kernel 8-wave rebalance — halve per-phase latency.)
typedef float v4 __attribute__((ext_vector_type(4)));
typedef short s8v __attribute__((ext_vector_type(8)));   // bf16x8 fragment
typedef float f4v __attribute__((ext_vector_type(4)));   // mfma C/D
typedef unsigned short u16;
typedef u16 us2 __attribute__((ext_vector_type(2)));
typedef u16 us4 __attribute__((ext_vector_type(4)));
typedef u16 us8 __attribute__((ext_vector_type(8)));

// workspace layout (float units)
#define OFF_PHIKB 0            // bf16 [8192][128]          (524288 f)
#define OFF_PHIQB 524288       // bf16 [8192][128]          (524288 f)
#define OFF_KVTB  1048576      // bf16 [4][128][32][128]    (1048576 f)
#define OFF_N32   2097152      // fp32 [4][32][128]         (16384 f)
#define OFF_MPRE  2113536      // bf16 [4][32][128][128]    (1048576 f)
#define OFF_NPRE  3162112      // fp32 [4][32][128]         (16384 f)
// total 3178496 floats = 12.7 MB

__device__ inline u16 f2bf(float f) {
  union { float f; unsigned u; } v; v.f = f;
  unsigned r = v.u + 0x7fffu + ((v.u >> 16) & 1u);
  return (u16)(r >> 16);
}
__device__ inline float bf2f(u16 h) {
  union { unsigned u; float f; } v; v.u = ((unsigned)h) << 16; return v.f;
}

// ---------------------------------------------------------------------------
// Kernel 1: fused phi (+ per-chunk KV/N for the K tensor).  L=64 chunk/block.
// Grid (128, 2): x = 64-row slab (=1 chunk), y = 0:K(+kv) / 1:Q.  512 thr.
// LDS: phase A Xb[64][136]@0, Wb[128][136]@8704 (u16);
//      phase B (K only) KdT[128][72]@0, Vt[128][72]@9216 (alias A; safe:
//      all writes happen after the post-MFMA barrier, no A-reads remain).
// ---------------------------------------------------------------------------
__global__ __launch_bounds__(512) void phikv_kernel(
    const float* __restrict__ K, const float* __restrict__ Q,
    const float* __restrict__ V, const float* __restrict__ W,
    u16* __restrict__ phiKb, u16* __restrict__ phiQb,
    u16* __restrict__ KVTb, float* __restrict__ N32) {
  __shared__ __align__(16) u16 smem[26112];
  __shared__ float srowsq[64];
  __shared__ float scl[64];
  u16* Xb = smem;
  u16* Wb = smem + 8704;
  u16* KdT = smem;          // phase B
  u16* Vt = smem + 9216;    // phase B

  const int tid = threadIdx.x;
  const bool isK = (blockIdx.y == 0);
  const float* X = isK ? K : Q;
  u16* outPhi = isK ? phiKb : phiQb;
  const int row0 = blockIdx.x * 64;
  const int wv = tid >> 6;   // 0..7
  const int lane = tid & 63;
  const int q = lane >> 4;
  const int ln = lane & 15;

  // ---- prefetch V row-pairs (K-blocks): enables conflict-free transpose ----
  v4 vpa[2], vpb[2];
  if (isK) {
#pragma unroll
    for (int k = 0; k < 2; k++) {
      int j = tid + k * 512;
      int s0 = (j & 31) * 2;
      int e4 = (j >> 5) * 4;  // 0..124
      vpa[k] = *(const v4*)&V[(size_t)(row0 + s0) * 128 + e4];
      vpb[k] = *(const v4*)&V[(size_t)(row0 + s0 + 1) * 128 + e4];
    }
  }

  // ---- stage X -> bf16 Xb + per-row sumsq (fp32, shuffle-reduced) ----
#pragma unroll
  for (int k = 0; k < 4; k++) {
    int j = tid + k * 512;
    int r = j >> 5;
    int c4 = (j & 31) * 4;
    v4 x = *(const v4*)&X[(size_t)(row0 + r) * 128 + c4];
    us4 xb;
    float p = 0.f;
#pragma unroll
    for (int i = 0; i < 4; i++) { xb[i] = f2bf(x[i]); p += x[i] * x[i]; }
    *(us4*)&Xb[r * 136 + c4] = xb;
    p += __shfl_down(p, 16, 32);
    p += __shfl_down(p, 8, 32);
    p += __shfl_down(p, 4, 32);
    p += __shfl_down(p, 2, 32);
    p += __shfl_down(p, 1, 32);
    if ((tid & 31) == 0) srowsq[r] = p;
  }
  // ---- stage W -> bf16 Wb ----
#pragma unroll
  for (int k = 0; k < 8; k++) {
    int j = tid + k * 512;
    int r = j >> 5;
    int c4 = (j & 31) * 4;
    v4 w = *(const v4*)&W[(size_t)r * 128 + c4];
    us4 wb;
#pragma unroll
    for (int i = 0; i < 4; i++) wb[i] = f2bf(w[i]);
    *(us4*)&Wb[r * 136 + c4] = wb;
  }
  __syncthreads();
  if (tid < 64)
    scl[tid] = 0.08838834764831845f * __expf(-0.5f * sqrtf(srowsq[tid]));

  // ---- phi MFMA: wave -> row-tile tr=wv>>1, col-tiles (wv&1)*4.. ----
  const int tr = wv >> 1;
  const int cb = (wv & 1) * 4;
  f4v acc[4];
#pragma unroll
  for (int i = 0; i < 4; i++) acc[i] = (f4v){0.f, 0.f, 0.f, 0.f};
#pragma unroll
  for (int ks = 0; ks < 4; ks++) {
    s8v a = *(const s8v*)&Xb[(tr * 16 + ln) * 136 + ks * 32 + q * 8];
#pragma unroll
    for (int i = 0; i < 4; i++) {
      s8v bb = *(const s8v*)&Wb[((cb + i) * 16 + ln) * 136 + ks * 32 + q * 8];
      acc[i] = __builtin_amdgcn_mfma_f32_16x16x32_bf16(a, bb, acc[i], 0, 0, 0);
    }
  }
  __syncthreads();  // Xb/Wb reads done (phase-B aliasing safe); scl ready

  // ---- epilogue: phi -> global direct + KdT (transposed, K-blocks) ----
#pragma unroll
  for (int i = 0; i < 4; i++) {
    const int ct = cb + i;
    us4 col;
#pragma unroll
    for (int r = 0; r < 4; r++) {
      int row = tr * 16 + q * 4 + r;
      u16 hv = f2bf(scl[row] * __expf(acc[i][r]));
      outPhi[(size_t)(row0 + row) * 128 + ct * 16 + ln] = hv;
      col[r] = hv;
    }
    if (isK) *(us4*)&KdT[(ct * 16 + ln) * 72 + tr * 16 + q * 4] = col;
  }
  if (!isK) return;  // Q-blocks: done (no further LDS phases)

  // ---- Vt from prefetch regs: us2 row-pair stores, conflict-free ----
#pragma unroll
  for (int k = 0; k < 2; k++) {
    int j = tid + k * 512;
    int s0 = (j & 31) * 2;
    int e4 = (j >> 5) * 4;
#pragma unroll
    for (int i = 0; i < 4; i++) {
      us2 w2 = {f2bf(vpa[k][i]), f2bf(vpb[k][i])};
      *(us2*)&Vt[(e4 + i) * 72 + s0] = w2;
    }
  }
  __syncthreads();

  const int b = row0 >> 11;
  const int c = (row0 >> 6) & 31;  // this block's chunk

  // ---- N sums over 64 rows (512-thr spread: 4 lanes/row, width-4 shfl) ----
  {
    const int t = tid >> 2;   // 0..127 (d index)
    const int p4 = tid & 3;
    float ns = 0.f;
    us8 v0 = *(const us8*)&KdT[t * 72 + p4 * 16];
    us8 v1 = *(const us8*)&KdT[t * 72 + p4 * 16 + 8];
#pragma unroll
    for (int i = 0; i < 8; i++) ns += bf2f(v0[i]) + bf2f(v1[i]);
    ns += __shfl_down(ns, 2, 4);
    ns += __shfl_down(ns, 1, 4);
    if (p4 == 0) N32[(size_t)(b * 32 + c) * 128 + t] = ns;
  }

  // ---- kv MFMA: KVT[e][d] = sum_{s<64} V[s][e]*phiK[s][d] ----
  {
    const int et = wv;  // 8 e-tiles / 8 waves
    s8v a0 = *(const s8v*)&Vt[(et * 16 + ln) * 72 + q * 8];
    s8v a1 = *(const s8v*)&Vt[(et * 16 + ln) * 72 + 32 + q * 8];
    f4v ac[8];
#pragma unroll
    for (int dt = 0; dt < 8; dt++) ac[dt] = (f4v){0.f, 0.f, 0.f, 0.f};
#pragma unroll
    for (int dt = 0; dt < 8; dt++) {
      s8v b0 = *(const s8v*)&KdT[(dt * 16 + ln) * 72 + q * 8];
      ac[dt] = __builtin_amdgcn_mfma_f32_16x16x32_bf16(a0, b0, ac[dt], 0, 0, 0);
      s8v b1 = *(const s8v*)&KdT[(dt * 16 + ln) * 72 + 32 + q * 8];
      ac[dt] = __builtin_amdgcn_mfma_f32_16x16x32_bf16(a1, b1, ac[dt], 0, 0, 0);
    }
#pragma unroll
    for (int dt = 0; dt < 8; dt++)
#pragma unroll
      for (int r = 0; r < 4; r++) {
        int e = et * 16 + q * 4 + r;
        int d = dt * 16 + ln;
        KVTb[((size_t)(b * 128 + e) * 32 + c) * 128 + d] = f2bf(ac[dt][r]);
      }
  }
}

// ---------------------------------------------------------------------------
// Kernel 1.5: exclusive chunk-prefix scan of KVT and N.
//  blocks 0..127: (b = id>>5, e-group = (id&31)*4) — 64 thr = 4 e x 16 d8.
//    fp32 accumulate over c (single bf16 rounding per output), exclusive
//    write-before-add.
//  blocks 128..131: N32 scan for batch b = id-128 (fp32, exact).
// ---------------------------------------------------------------------------
__global__ __launch_bounds__(64) void scan_kernel(
    const u16* __restrict__ KVTb, const float* __restrict__ N32,
    u16* __restrict__ Mpre, float* __restrict__ Npre) {
  const int id = blockIdx.x;
  const int tid = threadIdx.x;
  if (id < 128) {
    const int b = id >> 5;
    const int e = (id & 31) * 4 + (tid >> 4);
    const int d8 = (tid & 15) * 8;
    const u16* src = &KVTb[((size_t)(b * 128 + e) * 32) * 128 + d8];
    u16* dst = &Mpre[((size_t)b * 32 * 128 + e) * 128 + d8];  // stride c: 16384
    float acc[8];
#pragma unroll
    for (int i = 0; i < 8; i++) acc[i] = 0.f;
    for (int base = 0; base < 32; base += 8) {
      us8 t[8];
#pragma unroll
      for (int u = 0; u < 8; u++) t[u] = *(const us8*)&src[(base + u) * 128];
#pragma unroll
      for (int u = 0; u < 8; u++) {
        us8 w;
#pragma unroll
        for (int i = 0; i < 8; i++) w[i] = f2bf(acc[i]);
        *(us8*)&dst[(size_t)(base + u) * 16384] = w;
#pragma unroll
        for (int i = 0; i < 8; i++) acc[i] += bf2f(t[u][i]);
      }
    }
  } else {
    const int b = id - 128;
    const float* src = &N32[(size_t)b * 32 * 128 + tid];
    float* dst = &Npre[(size_t)b * 32 * 128 + tid];
    float a0 = 0.f, a1 = 0.f;
    for (int cc = 0; cc < 32; cc++) {
      dst[cc * 128] = a0;
      dst[cc * 128 + 64] = a1;
      a0 += src[cc * 128];
      a1 += src[cc * 128 + 64];
    }
  }
}

// ---------------------------------------------------------------------------
// Kernel 2: outputs.  Block id = c*16 + (b*4+h): same-(b,h) blocks differ by
// 16 (≡0 mod 8) -> same XCD under round-robin placement.  512 thr = 8 waves:
// QK^T 2 tiles/wave (balanced, zero-tiles written), PV/QM 1 combo/wave.
// Grid 512, 2 blk/CU (16 waves/CU).
// ---------------------------------------------------------------------------
__global__ __launch_bounds__(512) void out_kernel(
    const u16* __restrict__ phiKb, const u16* __restrict__ phiQb,
    const float* __restrict__ V, const u16* __restrict__ Mpre,
    const float* __restrict__ Npre, float* __restrict__ out) {
  __shared__ __align__(16) u16 Qs[64 * 136];  // [t][d]
  __shared__ __align__(16) u16 Ks[64 * 136];  // [s][d]
  __shared__ __align__(16) u16 Ms[32 * 136];  // M^T prefix rows of quarter
  __shared__ __align__(16) u16 Vt[32 * 72];   // [e][s]
  __shared__ __align__(16) u16 Ps[64 * 72];   // [t][s], masked
  __shared__ float Ns[128];
  __shared__ float rs[64];

  const int tid = threadIdx.x;
  const int id = blockIdx.x;
  const int c = id >> 4;         // chunk 0..31
  const int g = id & 15;         // (b,h) group -> XCD-stable
  const int b = g >> 2;
  const int h = g & 3;
  const int srow0 = b * 2048 + c * 64;
  const int ecol0 = h * 32;
  const int wv = tid >> 6;       // 0..7
  const int lane = tid & 63;
  const int q = lane >> 4;
  const int ln = lane & 15;

  // ---- V prefetch: one v4 per thread (row vs, 4-col group) ----
  const int vs = tid & 63;
  const int ve4 = (tid >> 6) * 4;  // 0..28
  v4 va = *(const v4*)&V[(size_t)(srow0 + vs) * 128 + ecol0 + ve4];

  // ---- stage Qs, Ks (64 x 128 bf16 each; 2 us8 per thread per tensor) ----
#pragma unroll
  for (int k = 0; k < 2; k++) {
    int j = tid + k * 512;  // 0..1023
    int t = j >> 4;
    int d8 = (j & 15) * 8;
    *(us8*)&Qs[t * 136 + d8] = *(const us8*)&phiQb[(size_t)(srow0 + t) * 128 + d8];
    *(us8*)&Ks[t * 136 + d8] = *(const us8*)&phiKb[(size_t)(srow0 + t) * 128 + d8];
  }

  // ---- exclusive M-prefix: precomputed, 1 coalesced us8 load ----
  {
    const int se = tid >> 4;          // 0..31
    const int sd8 = (tid & 15) * 8;
    *(us8*)&Ms[se * 136 + sd8] =
        *(const us8*)&Mpre[((size_t)(b * 32 + c) * 128 + ecol0 + se) * 128 + sd8];
  }
  // ---- exclusive N-prefix: precomputed ----
  if (tid < 128) Ns[tid] = Npre[(size_t)(b * 32 + c) * 128 + tid];
  // ---- Vt: transposed scalar stores (lanes consecutive: conflict-free) ----
#pragma unroll
  for (int i = 0; i < 4; i++) Vt[(ve4 + i) * 72 + vs] = f2bf(va[i]);
  __syncthreads();

  // ---- P = Q.K^T: 16 tiles over 8 waves (2 each; tc>tr tiles store 0) ----
#pragma unroll
  for (int mi = 0; mi < 2; mi++) {
    const int m = wv * 2 + mi;
    const int tr = m >> 2;
    const int tc = m & 3;
    f4v acc = {0.f, 0.f, 0.f, 0.f};
    if (tc <= tr) {
#pragma unroll
      for (int ks = 0; ks < 4; ks++) {
        s8v a = *(const s8v*)&Qs[(tr * 16 + ln) * 136 + ks * 32 + q * 8];
        s8v bb = *(const s8v*)&Ks[(tc * 16 + ln) * 136 + ks * 32 + q * 8];
        acc = __builtin_amdgcn_mfma_f32_16x16x32_bf16(a, bb, acc, 0, 0, 0);
      }
    }
    const int s_g = tc * 16 + ln;
#pragma unroll
    for (int r = 0; r < 4; r++) {
      int t_g = tr * 16 + q * 4 + r;
      Ps[t_g * 72 + s_g] = f2bf(s_g <= t_g ? acc[r] : 0.f);
    }
  }
  __syncthreads();

  // ---- denominators: rs[t] = rowsum(P) + Q[t,:].Ns  (8 lanes/row) ----
  {
    const int t = tid >> 3;    // 0..63
    const int p8 = tid & 7;
    float rsl = 0.f;
    us8 pa = *(const us8*)&Ps[t * 72 + p8 * 8];
#pragma unroll
    for (int i = 0; i < 8; i++) rsl += bf2f(pa[i]);
#pragma unroll
    for (int kk = 0; kk < 2; kk++) {
      us8 qv = *(const us8*)&Qs[t * 136 + p8 * 16 + kk * 8];
#pragma unroll
      for (int i = 0; i < 8; i++)
        rsl += bf2f(qv[i]) * Ns[p8 * 16 + kk * 8 + i];
    }
    rsl += __shfl_down(rsl, 4, 8);
    rsl += __shfl_down(rsl, 2, 8);
    rsl += __shfl_down(rsl, 1, 8);
    if (p8 == 0) rs[t] = rsl;
  }

  // ---- out = P@V + Q@M: 1 combo/wave (tr2 = wv>>1, et = wv&1) ----
  const int tr2 = wv >> 1;
  const int et = wv & 1;
  f4v acc2 = {0.f, 0.f, 0.f, 0.f};
#pragma unroll
  for (int ks2 = 0; ks2 < 2; ks2++) {
    s8v a_p = *(const s8v*)&Ps[(tr2 * 16 + ln) * 72 + ks2 * 32 + q * 8];
    s8v b_v = *(const s8v*)&Vt[(et * 16 + ln) * 72 + ks2 * 32 + q * 8];
    acc2 = __builtin_amdgcn_mfma_f32_16x16x32_bf16(a_p, b_v, acc2, 0, 0, 0);
  }
#pragma unroll
  for (int ks = 0; ks < 4; ks++) {
    s8v a_q = *(const s8v*)&Qs[(tr2 * 16 + ln) * 136 + ks * 32 + q * 8];
    s8v b_m = *(const s8v*)&Ms[(et * 16 + ln) * 136 + ks * 32 + q * 8];
    acc2 = __builtin_amdgcn_mfma_f32_16x16x32_bf16(a_q, b_m, acc2, 0, 0, 0);
  }
  __syncthreads();  // rs ready

  // ---- epilogue ----
#pragma unroll
  for (int r = 0; r < 4; r++) {
    int t_g = tr2 * 16 + q * 4 + r;
    float rv = rs[t_g];
    float den = rv + (rv > 0.f ? 1e-6f : (rv < 0.f ? -1e-6f : 0.f));
    out[(size_t)(srow0 + t_g) * 128 + ecol0 + et * 16 + ln] = acc2[r] / den;
  }
}

// ---------------------------------------------------------------------------
extern "C" void kernel_launch(void* const* d_in, const int* in_sizes, int n_in,
                              void* d_out, int out_size, void* d_ws,
                              size_t ws_size, hipStream_t stream) {
  (void)in_sizes; (void)n_in; (void)out_size; (void)ws_size;
  const float* K = (const float*)d_in[0];
  const float* Q = (const float*)d_in[1];
  const float* V = (const float*)d_in[2];
  const float* W = (const float*)d_in[6];
  float* out = (float*)d_out;
  float* ws = (float*)d_ws;

  u16* phiKb = (u16*)(ws + OFF_PHIKB);
  u16* phiQb = (u16*)(ws + OFF_PHIQB);
  u16* KVTb = (u16*)(ws + OFF_KVTB);
  float* N32 = ws + OFF_N32;
  u16* Mpre = (u16*)(ws + OFF_MPRE);
  float* Npre = ws + OFF_NPRE;

  phikv_kernel<<<dim3(128, 2), 512, 0, stream>>>(K, Q, V, W, phiKb, phiQb,
                                                 KVTb, N32);
  scan_kernel<<<132, 64, 0, stream>>>(KVTb, N32, Mpre, Npre);
  out_kernel<<<512, 512, 0, stream>>>(phiKb, phiQb, V, Mpre, Npre, out);
}

// Round 4
// 92.249 us; speedup vs baseline: 1.0018x; 1.0018x over previous
//
#include <hip/hip_runtime.h>

// Performer causal linear attention — 3-dispatch bf16-MFMA pipeline, L=64.
// B=4, S=2048, D=128; chunks of L=64 (128 chunks, 32/batch).
//  phikv (256 blk x 512 thr): phi = scale*exp(W@x) via MFMA; phi stored to
//         global DIRECTLY from acc regs; K-blocks also emit per-chunk
//         KVT[e][d] (bf16, [b][e][c][d]) + N[d] (fp32, 512-thr spread).
//  scan  (132 blk x 64 thr): exclusive chunk-prefix of KVT -> Mpre
//         (bf16 [b][c][e][d], fp32-accumulated) and N32 -> Npre (fp32).
//  out (512 blk x 256 thr, 2 blk/CU): Mpre/Npre direct loads, P=QK^T
//         (4 waves, tc<=tr), out = P@V + Q@M; denominators computed
//         IN-WAVE (quad-shuffle, no rs[] LDS, no final barrier).
// (R5: grid barriers ~100us.  R10: scan dispatch -4.3us.  R11: shaves
//  -1.4us.  R12: 8-wave out REGRESSED +0.8 — barrier cost > phase split;
//  reverted.  This round: R2 structure + in-wave denominators.)
typedef float v4 __attribute__((ext_vector_type(4)));
typedef short s8v __attribute__((ext_vector_type(8)));   // bf16x8 fragment
typedef float f4v __attribute__((ext_vector_type(4)));   // mfma C/D
typedef unsigned short u16;
typedef u16 us2 __attribute__((ext_vector_type(2)));
typedef u16 us4 __attribute__((ext_vector_type(4)));
typedef u16 us8 __attribute__((ext_vector_type(8)));

// workspace layout (float units)
#define OFF_PHIKB 0            // bf16 [8192][128]          (524288 f)
#define OFF_PHIQB 524288       // bf16 [8192][128]          (524288 f)
#define OFF_KVTB  1048576      // bf16 [4][128][32][128]    (1048576 f)
#define OFF_N32   2097152      // fp32 [4][32][128]         (16384 f)
#define OFF_MPRE  2113536      // bf16 [4][32][128][128]    (1048576 f)
#define OFF_NPRE  3162112      // fp32 [4][32][128]         (16384 f)
// total 3178496 floats = 12.7 MB

__device__ inline u16 f2bf(float f) {
  union { float f; unsigned u; } v; v.f = f;
  unsigned r = v.u + 0x7fffu + ((v.u >> 16) & 1u);
  return (u16)(r >> 16);
}
__device__ inline float bf2f(u16 h) {
  union { unsigned u; float f; } v; v.u = ((unsigned)h) << 16; return v.f;
}

// ---------------------------------------------------------------------------
// Kernel 1: fused phi (+ per-chunk KV/N for the K tensor).  L=64 chunk/block.
// Grid (128, 2): x = 64-row slab (=1 chunk), y = 0:K(+kv) / 1:Q.  512 thr.
// LDS: phase A Xb[64][136]@0, Wb[128][136]@8704 (u16);
//      phase B (K only) KdT[128][72]@0, Vt[128][72]@9216 (alias A; safe:
//      all writes happen after the post-MFMA barrier, no A-reads remain).
// ---------------------------------------------------------------------------
__global__ __launch_bounds__(512) void phikv_kernel(
    const float* __restrict__ K, const float* __restrict__ Q,
    const float* __restrict__ V, const float* __restrict__ W,
    u16* __restrict__ phiKb, u16* __restrict__ phiQb,
    u16* __restrict__ KVTb, float* __restrict__ N32) {
  __shared__ __align__(16) u16 smem[26112];
  __shared__ float srowsq[64];
  __shared__ float scl[64];
  u16* Xb = smem;
  u16* Wb = smem + 8704;
  u16* KdT = smem;          // phase B
  u16* Vt = smem + 9216;    // phase B

  const int tid = threadIdx.x;
  const bool isK = (blockIdx.y == 0);
  const float* X = isK ? K : Q;
  u16* outPhi = isK ? phiKb : phiQb;
  const int row0 = blockIdx.x * 64;
  const int wv = tid >> 6;   // 0..7
  const int lane = tid & 63;
  const int q = lane >> 4;
  const int ln = lane & 15;

  // ---- prefetch V row-pairs (K-blocks): enables conflict-free transpose ----
  v4 vpa[2], vpb[2];
  if (isK) {
#pragma unroll
    for (int k = 0; k < 2; k++) {
      int j = tid + k * 512;
      int s0 = (j & 31) * 2;
      int e4 = (j >> 5) * 4;  // 0..124
      vpa[k] = *(const v4*)&V[(size_t)(row0 + s0) * 128 + e4];
      vpb[k] = *(const v4*)&V[(size_t)(row0 + s0 + 1) * 128 + e4];
    }
  }

  // ---- stage X -> bf16 Xb + per-row sumsq (fp32, shuffle-reduced) ----
#pragma unroll
  for (int k = 0; k < 4; k++) {
    int j = tid + k * 512;
    int r = j >> 5;
    int c4 = (j & 31) * 4;
    v4 x = *(const v4*)&X[(size_t)(row0 + r) * 128 + c4];
    us4 xb;
    float p = 0.f;
#pragma unroll
    for (int i = 0; i < 4; i++) { xb[i] = f2bf(x[i]); p += x[i] * x[i]; }
    *(us4*)&Xb[r * 136 + c4] = xb;
    p += __shfl_down(p, 16, 32);
    p += __shfl_down(p, 8, 32);
    p += __shfl_down(p, 4, 32);
    p += __shfl_down(p, 2, 32);
    p += __shfl_down(p, 1, 32);
    if ((tid & 31) == 0) srowsq[r] = p;
  }
  // ---- stage W -> bf16 Wb ----
#pragma unroll
  for (int k = 0; k < 8; k++) {
    int j = tid + k * 512;
    int r = j >> 5;
    int c4 = (j & 31) * 4;
    v4 w = *(const v4*)&W[(size_t)r * 128 + c4];
    us4 wb;
#pragma unroll
    for (int i = 0; i < 4; i++) wb[i] = f2bf(w[i]);
    *(us4*)&Wb[r * 136 + c4] = wb;
  }
  __syncthreads();
  if (tid < 64)
    scl[tid] = 0.08838834764831845f * __expf(-0.5f * sqrtf(srowsq[tid]));

  // ---- phi MFMA: wave -> row-tile tr=wv>>1, col-tiles (wv&1)*4.. ----
  const int tr = wv >> 1;
  const int cb = (wv & 1) * 4;
  f4v acc[4];
#pragma unroll
  for (int i = 0; i < 4; i++) acc[i] = (f4v){0.f, 0.f, 0.f, 0.f};
#pragma unroll
  for (int ks = 0; ks < 4; ks++) {
    s8v a = *(const s8v*)&Xb[(tr * 16 + ln) * 136 + ks * 32 + q * 8];
#pragma unroll
    for (int i = 0; i < 4; i++) {
      s8v bb = *(const s8v*)&Wb[((cb + i) * 16 + ln) * 136 + ks * 32 + q * 8];
      acc[i] = __builtin_amdgcn_mfma_f32_16x16x32_bf16(a, bb, acc[i], 0, 0, 0);
    }
  }
  __syncthreads();  // Xb/Wb reads done (phase-B aliasing safe); scl ready

  // ---- epilogue: phi -> global direct + KdT (transposed, K-blocks) ----
#pragma unroll
  for (int i = 0; i < 4; i++) {
    const int ct = cb + i;
    us4 col;
#pragma unroll
    for (int r = 0; r < 4; r++) {
      int row = tr * 16 + q * 4 + r;
      u16 hv = f2bf(scl[row] * __expf(acc[i][r]));
      outPhi[(size_t)(row0 + row) * 128 + ct * 16 + ln] = hv;
      col[r] = hv;
    }
    if (isK) *(us4*)&KdT[(ct * 16 + ln) * 72 + tr * 16 + q * 4] = col;
  }
  if (!isK) return;  // Q-blocks: done (no further LDS phases)

  // ---- Vt from prefetch regs: us2 row-pair stores, conflict-free ----
#pragma unroll
  for (int k = 0; k < 2; k++) {
    int j = tid + k * 512;
    int s0 = (j & 31) * 2;
    int e4 = (j >> 5) * 4;
#pragma unroll
    for (int i = 0; i < 4; i++) {
      us2 w2 = {f2bf(vpa[k][i]), f2bf(vpb[k][i])};
      *(us2*)&Vt[(e4 + i) * 72 + s0] = w2;
    }
  }
  __syncthreads();

  const int b = row0 >> 11;
  const int c = (row0 >> 6) & 31;  // this block's chunk

  // ---- N sums over 64 rows (512-thr spread: 4 lanes/row, width-4 shfl) ----
  {
    const int t = tid >> 2;   // 0..127 (d index)
    const int p4 = tid & 3;
    float ns = 0.f;
    us8 v0 = *(const us8*)&KdT[t * 72 + p4 * 16];
    us8 v1 = *(const us8*)&KdT[t * 72 + p4 * 16 + 8];
#pragma unroll
    for (int i = 0; i < 8; i++) ns += bf2f(v0[i]) + bf2f(v1[i]);
    ns += __shfl_down(ns, 2, 4);
    ns += __shfl_down(ns, 1, 4);
    if (p4 == 0) N32[(size_t)(b * 32 + c) * 128 + t] = ns;
  }

  // ---- kv MFMA: KVT[e][d] = sum_{s<64} V[s][e]*phiK[s][d] ----
  {
    const int et = wv;  // 8 e-tiles / 8 waves
    s8v a0 = *(const s8v*)&Vt[(et * 16 + ln) * 72 + q * 8];
    s8v a1 = *(const s8v*)&Vt[(et * 16 + ln) * 72 + 32 + q * 8];
    f4v ac[8];
#pragma unroll
    for (int dt = 0; dt < 8; dt++) ac[dt] = (f4v){0.f, 0.f, 0.f, 0.f};
#pragma unroll
    for (int dt = 0; dt < 8; dt++) {
      s8v b0 = *(const s8v*)&KdT[(dt * 16 + ln) * 72 + q * 8];
      ac[dt] = __builtin_amdgcn_mfma_f32_16x16x32_bf16(a0, b0, ac[dt], 0, 0, 0);
      s8v b1 = *(const s8v*)&KdT[(dt * 16 + ln) * 72 + 32 + q * 8];
      ac[dt] = __builtin_amdgcn_mfma_f32_16x16x32_bf16(a1, b1, ac[dt], 0, 0, 0);
    }
#pragma unroll
    for (int dt = 0; dt < 8; dt++)
#pragma unroll
      for (int r = 0; r < 4; r++) {
        int e = et * 16 + q * 4 + r;
        int d = dt * 16 + ln;
        KVTb[((size_t)(b * 128 + e) * 32 + c) * 128 + d] = f2bf(ac[dt][r]);
      }
  }
}

// ---------------------------------------------------------------------------
// Kernel 1.5: exclusive chunk-prefix scan of KVT and N.
//  blocks 0..127: (b = id>>5, e-group = (id&31)*4) — 64 thr = 4 e x 16 d8.
//    fp32 accumulate over c (single bf16 rounding per output), exclusive
//    write-before-add.
//  blocks 128..131: N32 scan for batch b = id-128 (fp32, exact).
// ---------------------------------------------------------------------------
__global__ __launch_bounds__(64) void scan_kernel(
    const u16* __restrict__ KVTb, const float* __restrict__ N32,
    u16* __restrict__ Mpre, float* __restrict__ Npre) {
  const int id = blockIdx.x;
  const int tid = threadIdx.x;
  if (id < 128) {
    const int b = id >> 5;
    const int e = (id & 31) * 4 + (tid >> 4);
    const int d8 = (tid & 15) * 8;
    const u16* src = &KVTb[((size_t)(b * 128 + e) * 32) * 128 + d8];
    u16* dst = &Mpre[((size_t)b * 32 * 128 + e) * 128 + d8];  // stride c: 16384
    float acc[8];
#pragma unroll
    for (int i = 0; i < 8; i++) acc[i] = 0.f;
    for (int base = 0; base < 32; base += 8) {
      us8 t[8];
#pragma unroll
      for (int u = 0; u < 8; u++) t[u] = *(const us8*)&src[(base + u) * 128];
#pragma unroll
      for (int u = 0; u < 8; u++) {
        us8 w;
#pragma unroll
        for (int i = 0; i < 8; i++) w[i] = f2bf(acc[i]);
        *(us8*)&dst[(size_t)(base + u) * 16384] = w;
#pragma unroll
        for (int i = 0; i < 8; i++) acc[i] += bf2f(t[u][i]);
      }
    }
  } else {
    const int b = id - 128;
    const float* src = &N32[(size_t)b * 32 * 128 + tid];
    float* dst = &Npre[(size_t)b * 32 * 128 + tid];
    float a0 = 0.f, a1 = 0.f;
    for (int cc = 0; cc < 32; cc++) {
      dst[cc * 128] = a0;
      dst[cc * 128 + 64] = a1;
      a0 += src[cc * 128];
      a1 += src[cc * 128 + 64];
    }
  }
}

// ---------------------------------------------------------------------------
// Kernel 2: outputs.  Block id = c*16 + (b*4+h): same-(b,h) blocks differ by
// 16 (≡0 mod 8) -> same XCD under round-robin placement.  256 thr = 4 waves
// (R2 structure).  Denominators computed in-wave (quad shuffles) — no rs[]
// LDS, no final barrier.  Grid 512, 2 blk/CU.
// ---------------------------------------------------------------------------
__global__ __launch_bounds__(256) void out_kernel(
    const u16* __restrict__ phiKb, const u16* __restrict__ phiQb,
    const float* __restrict__ V, const u16* __restrict__ Mpre,
    const float* __restrict__ Npre, float* __restrict__ out) {
  __shared__ __align__(16) u16 Qs[64 * 136];  // [t][d]
  __shared__ __align__(16) u16 Ks[64 * 136];  // [s][d]
  __shared__ __align__(16) u16 Ms[32 * 136];  // M^T prefix rows of quarter
  __shared__ __align__(16) u16 Vt[32 * 72];   // [e][s]
  __shared__ __align__(16) u16 Ps[64 * 72];   // [t][s], masked
  __shared__ float Ns[128];

  const int tid = threadIdx.x;
  const int id = blockIdx.x;
  const int c = id >> 4;         // chunk 0..31
  const int g = id & 15;         // (b,h) group -> XCD-stable
  const int b = g >> 2;
  const int h = g & 3;
  const int srow0 = b * 2048 + c * 64;
  const int ecol0 = h * 32;
  const int wv = tid >> 6;
  const int lane = tid & 63;
  const int q = lane >> 4;
  const int ln = lane & 15;

  // ---- V prefetch (row-pairs of this 32-col quarter) ----
  const int vs0 = (tid & 31) * 2;
  const int ve4 = (tid >> 5) * 4;  // 0..28
  v4 va = *(const v4*)&V[(size_t)(srow0 + vs0) * 128 + ecol0 + ve4];
  v4 vb = *(const v4*)&V[(size_t)(srow0 + vs0 + 1) * 128 + ecol0 + ve4];

  // ---- stage Qs, Ks (64 x 128 bf16 each) ----
#pragma unroll
  for (int k = 0; k < 4; k++) {
    int j = tid + k * 256;  // 0..1023
    int t = j >> 4;
    int d8 = (j & 15) * 8;
    *(us8*)&Qs[t * 136 + d8] = *(const us8*)&phiQb[(size_t)(srow0 + t) * 128 + d8];
    *(us8*)&Ks[t * 136 + d8] = *(const us8*)&phiKb[(size_t)(srow0 + t) * 128 + d8];
  }

  // ---- exclusive M-prefix: precomputed, 2 coalesced us8 loads ----
  {
    const int se = tid >> 4;          // 0..15
    const int sd8 = (tid & 15) * 8;
    const u16* mp = &Mpre[((size_t)(b * 32 + c) * 128 + ecol0) * 128 + sd8];
    *(us8*)&Ms[se * 136 + sd8] = *(const us8*)&mp[se * 128];
    *(us8*)&Ms[(16 + se) * 136 + sd8] = *(const us8*)&mp[(16 + se) * 128];
  }
  // ---- exclusive N-prefix: precomputed ----
  if (tid < 128) Ns[tid] = Npre[(size_t)(b * 32 + c) * 128 + tid];
  // ---- Vt: us2 row-pair stores, conflict-free ----
#pragma unroll
  for (int i = 0; i < 4; i++) {
    us2 w2 = {f2bf(va[i]), f2bf(vb[i])};
    *(us2*)&Vt[(ve4 + i) * 72 + vs0] = w2;
  }
  __syncthreads();

  // ---- P = Q.K^T (wave = row-tile tr=wv; tc 0..3, causal) ----
  {
    const int tr = wv;
    for (int tc = 0; tc < 4; tc++) {  // wave-uniform bound
      f4v acc = {0.f, 0.f, 0.f, 0.f};
      if (tc <= tr) {
#pragma unroll
        for (int ks = 0; ks < 4; ks++) {
          s8v a = *(const s8v*)&Qs[(tr * 16 + ln) * 136 + ks * 32 + q * 8];
          s8v bb = *(const s8v*)&Ks[(tc * 16 + ln) * 136 + ks * 32 + q * 8];
          acc = __builtin_amdgcn_mfma_f32_16x16x32_bf16(a, bb, acc, 0, 0, 0);
        }
      }
      const int s_g = tc * 16 + ln;
#pragma unroll
      for (int r = 0; r < 4; r++) {
        int t_g = tr * 16 + q * 4 + r;
        Ps[t_g * 72 + s_g] = f2bf(s_g <= t_g ? acc[r] : 0.f);
      }
    }
  }
  __syncthreads();

  // ---- out = P@V + Q@M with IN-WAVE denominators (no barrier after) ----
  // Each wave handles tiles tr2 in {wv>>1, wv>>1+2}, et = wv&1.  For each
  // tile it also computes rs[row] for its 16 rows: 4 lanes/row (tl4 =
  // lane>>2, p4 = lane&3), quad shuffle-reduce; epilogue gathers via
  // __shfl from lane q*16 + r*4 (p4==0 holder of row q*4+r).
  const int et = wv & 1;
  const int tl4 = lane >> 2;  // 0..15 row-in-tile for denom
  const int p4 = lane & 3;
  f4v acc2[2];
  float rsv[2];
#pragma unroll
  for (int i = 0; i < 2; i++) {
    const int tr2 = (wv >> 1) + 2 * i;
    // denom partial for row t_d = tr2*16 + tl4
    const int t_d = tr2 * 16 + tl4;
    float rsl = 0.f;
    us8 pa = *(const us8*)&Ps[t_d * 72 + p4 * 16];
    us8 pb = *(const us8*)&Ps[t_d * 72 + p4 * 16 + 8];
#pragma unroll
    for (int e2 = 0; e2 < 8; e2++) rsl += bf2f(pa[e2]) + bf2f(pb[e2]);
#pragma unroll
    for (int kk = 0; kk < 4; kk++) {
      us8 qv = *(const us8*)&Qs[t_d * 136 + p4 * 32 + kk * 8];
#pragma unroll
      for (int e2 = 0; e2 < 8; e2++)
        rsl += bf2f(qv[e2]) * Ns[p4 * 32 + kk * 8 + e2];
    }
    rsl += __shfl_down(rsl, 2, 4);
    rsl += __shfl_down(rsl, 1, 4);
    rsv[i] = rsl;  // valid at p4==0 lanes (lane = 4*row_in_tile)

    // MFMA: P@V + Q@M for this tile
    acc2[i] = (f4v){0.f, 0.f, 0.f, 0.f};
#pragma unroll
    for (int ks2 = 0; ks2 < 2; ks2++) {
      s8v a_p = *(const s8v*)&Ps[(tr2 * 16 + ln) * 72 + ks2 * 32 + q * 8];
      s8v b_v = *(const s8v*)&Vt[(et * 16 + ln) * 72 + ks2 * 32 + q * 8];
      acc2[i] = __builtin_amdgcn_mfma_f32_16x16x32_bf16(a_p, b_v, acc2[i], 0, 0, 0);
    }
#pragma unroll
    for (int ks = 0; ks < 4; ks++) {
      s8v a_q = *(const s8v*)&Qs[(tr2 * 16 + ln) * 136 + ks * 32 + q * 8];
      s8v b_m = *(const s8v*)&Ms[(et * 16 + ln) * 136 + ks * 32 + q * 8];
      acc2[i] = __builtin_amdgcn_mfma_f32_16x16x32_bf16(a_q, b_m, acc2[i], 0, 0, 0);
    }
  }

  // ---- epilogue (in-wave rs gather; no __syncthreads needed) ----
#pragma unroll
  for (int i = 0; i < 2; i++) {
    const int tr2 = (wv >> 1) + 2 * i;
#pragma unroll
    for (int r = 0; r < 4; r++) {
      int t_g = tr2 * 16 + q * 4 + r;
      float rv = __shfl(rsv[i], q * 16 + r * 4);
      float den = rv + (rv > 0.f ? 1e-6f : (rv < 0.f ? -1e-6f : 0.f));
      out[(size_t)(srow0 + t_g) * 128 + ecol0 + et * 16 + ln] =
          acc2[i][r] / den;
    }
  }
}

// ---------------------------------------------------------------------------
extern "C" void kernel_launch(void* const* d_in, const int* in_sizes, int n_in,
                              void* d_out, int out_size, void* d_ws,
                              size_t ws_size, hipStream_t stream) {
  (void)in_sizes; (void)n_in; (void)out_size; (void)ws_size;
  const float* K = (const float*)d_in[0];
  const float* Q = (const float*)d_in[1];
  const float* V = (const float*)d_in[2];
  const float* W = (const float*)d_in[6];
  float* out = (float*)d_out;
  float* ws = (float*)d_ws;

  u16* phiKb = (u16*)(ws + OFF_PHIKB);
  u16* phiQb = (u16*)(ws + OFF_PHIQB);
  u16* KVTb = (u16*)(ws + OFF_KVTB);
  float* N32 = ws + OFF_N32;
  u16* Mpre = (u16*)(ws + OFF_MPRE);
  float* Npre = ws + OFF_NPRE;

  phikv_kernel<<<dim3(128, 2), 512, 0, stream>>>(K, Q, V, W, phiKb, phiQb,
                                                 KVTb, N32);
  scan_kernel<<<132, 64, 0, stream>>>(KVTb, N32, Mpre, Npre);
  out_kernel<<<512, 256, 0, stream>>>(phiKb, phiQb, V, Mpre, Npre, out);
}

// Round 5
// 91.186 us; speedup vs baseline: 1.0135x; 1.0117x over previous
//
#include <hip/hip_runtime.h>

// Performer causal linear attention — 3-dispatch bf16-MFMA pipeline, L=64.
// B=4, S=2048, D=128; chunks of L=64 (128 chunks, 32/batch).
//  phikv (256 blk x 512 thr): phi = scale*exp(W@x) via MFMA; phi stored to
//         global DIRECTLY from acc regs; K-blocks also emit per-chunk
//         KVT[e][d] (bf16, [b][e][c][d]) + N[d] (fp32).
//  scan  (132 blk x 128 thr): exclusive chunk-prefix of KVT -> Mpre
//         (bf16 [b][c][e][d], fp32-accumulated) and N32 -> Npre (fp32).
//         M-path: 32-KB linear LDS stage (independent coalesced loads, ONE
//         L2-latency exposure) then per-thread serial scan from LDS.
//  out (512 blk x 256 thr, 2 blk/CU): byte-identical to R2's 91.6us version
//         (rs[] LDS denominators; R3 8-wave and R4 in-wave variants both
//         regressed — reverted).
// (R5: grid barriers ~100us.  R10: scan dispatch -4.3us.  R11: shaves
//  -1.4us -> 91.6.  R12/R13: out_kernel restructures regressed; reverted.)
typedef float v4 __attribute__((ext_vector_type(4)));
typedef short s8v __attribute__((ext_vector_type(8)));   // bf16x8 fragment
typedef float f4v __attribute__((ext_vector_type(4)));   // mfma C/D
typedef unsigned short u16;
typedef u16 us2 __attribute__((ext_vector_type(2)));
typedef u16 us4 __attribute__((ext_vector_type(4)));
typedef u16 us8 __attribute__((ext_vector_type(8)));

// workspace layout (float units)
#define OFF_PHIKB 0            // bf16 [8192][128]          (524288 f)
#define OFF_PHIQB 524288       // bf16 [8192][128]          (524288 f)
#define OFF_KVTB  1048576      // bf16 [4][128][32][128]    (1048576 f)
#define OFF_N32   2097152      // fp32 [4][32][128]         (16384 f)
#define OFF_MPRE  2113536      // bf16 [4][32][128][128]    (1048576 f)
#define OFF_NPRE  3162112      // fp32 [4][32][128]         (16384 f)
// total 3178496 floats = 12.7 MB

__device__ inline u16 f2bf(float f) {
  union { float f; unsigned u; } v; v.f = f;
  unsigned r = v.u + 0x7fffu + ((v.u >> 16) & 1u);
  return (u16)(r >> 16);
}
__device__ inline float bf2f(u16 h) {
  union { unsigned u; float f; } v; v.u = ((unsigned)h) << 16; return v.f;
}

// ---------------------------------------------------------------------------
// Kernel 1: fused phi (+ per-chunk KV/N for the K tensor).  L=64 chunk/block.
// Grid (128, 2): x = 64-row slab (=1 chunk), y = 0:K(+kv) / 1:Q.  512 thr.
// LDS: phase A Xb[64][136]@0, Wb[128][136]@8704 (u16);
//      phase B (K only) KdT[128][72]@0, Vt[128][72]@9216 (alias A; safe:
//      all writes happen after the post-MFMA barrier, no A-reads remain).
// ---------------------------------------------------------------------------
__global__ __launch_bounds__(512) void phikv_kernel(
    const float* __restrict__ K, const float* __restrict__ Q,
    const float* __restrict__ V, const float* __restrict__ W,
    u16* __restrict__ phiKb, u16* __restrict__ phiQb,
    u16* __restrict__ KVTb, float* __restrict__ N32) {
  __shared__ __align__(16) u16 smem[26112];
  __shared__ float srowsq[64];
  __shared__ float scl[64];
  u16* Xb = smem;
  u16* Wb = smem + 8704;
  u16* KdT = smem;          // phase B
  u16* Vt = smem + 9216;    // phase B

  const int tid = threadIdx.x;
  const bool isK = (blockIdx.y == 0);
  const float* X = isK ? K : Q;
  u16* outPhi = isK ? phiKb : phiQb;
  const int row0 = blockIdx.x * 64;
  const int wv = tid >> 6;   // 0..7
  const int lane = tid & 63;
  const int q = lane >> 4;
  const int ln = lane & 15;

  // ---- prefetch V row-pairs (K-blocks): enables conflict-free transpose ----
  v4 vpa[2], vpb[2];
  if (isK) {
#pragma unroll
    for (int k = 0; k < 2; k++) {
      int j = tid + k * 512;
      int s0 = (j & 31) * 2;
      int e4 = (j >> 5) * 4;  // 0..124
      vpa[k] = *(const v4*)&V[(size_t)(row0 + s0) * 128 + e4];
      vpb[k] = *(const v4*)&V[(size_t)(row0 + s0 + 1) * 128 + e4];
    }
  }

  // ---- stage X -> bf16 Xb + per-row sumsq (fp32, shuffle-reduced) ----
#pragma unroll
  for (int k = 0; k < 4; k++) {
    int j = tid + k * 512;
    int r = j >> 5;
    int c4 = (j & 31) * 4;
    v4 x = *(const v4*)&X[(size_t)(row0 + r) * 128 + c4];
    us4 xb;
    float p = 0.f;
#pragma unroll
    for (int i = 0; i < 4; i++) { xb[i] = f2bf(x[i]); p += x[i] * x[i]; }
    *(us4*)&Xb[r * 136 + c4] = xb;
    p += __shfl_down(p, 16, 32);
    p += __shfl_down(p, 8, 32);
    p += __shfl_down(p, 4, 32);
    p += __shfl_down(p, 2, 32);
    p += __shfl_down(p, 1, 32);
    if ((tid & 31) == 0) srowsq[r] = p;
  }
  // ---- stage W -> bf16 Wb ----
#pragma unroll
  for (int k = 0; k < 8; k++) {
    int j = tid + k * 512;
    int r = j >> 5;
    int c4 = (j & 31) * 4;
    v4 w = *(const v4*)&W[(size_t)r * 128 + c4];
    us4 wb;
#pragma unroll
    for (int i = 0; i < 4; i++) wb[i] = f2bf(w[i]);
    *(us4*)&Wb[r * 136 + c4] = wb;
  }
  __syncthreads();
  if (tid < 64)
    scl[tid] = 0.08838834764831845f * __expf(-0.5f * sqrtf(srowsq[tid]));

  // ---- phi MFMA: wave -> row-tile tr=wv>>1, col-tiles (wv&1)*4.. ----
  const int tr = wv >> 1;
  const int cb = (wv & 1) * 4;
  f4v acc[4];
#pragma unroll
  for (int i = 0; i < 4; i++) acc[i] = (f4v){0.f, 0.f, 0.f, 0.f};
#pragma unroll
  for (int ks = 0; ks < 4; ks++) {
    s8v a = *(const s8v*)&Xb[(tr * 16 + ln) * 136 + ks * 32 + q * 8];
#pragma unroll
    for (int i = 0; i < 4; i++) {
      s8v bb = *(const s8v*)&Wb[((cb + i) * 16 + ln) * 136 + ks * 32 + q * 8];
      acc[i] = __builtin_amdgcn_mfma_f32_16x16x32_bf16(a, bb, acc[i], 0, 0, 0);
    }
  }
  __syncthreads();  // Xb/Wb reads done (phase-B aliasing safe); scl ready

  // ---- epilogue: phi -> global direct + KdT (transposed, K-blocks) ----
#pragma unroll
  for (int i = 0; i < 4; i++) {
    const int ct = cb + i;
    us4 col;
#pragma unroll
    for (int r = 0; r < 4; r++) {
      int row = tr * 16 + q * 4 + r;
      u16 hv = f2bf(scl[row] * __expf(acc[i][r]));
      outPhi[(size_t)(row0 + row) * 128 + ct * 16 + ln] = hv;
      col[r] = hv;
    }
    if (isK) *(us4*)&KdT[(ct * 16 + ln) * 72 + tr * 16 + q * 4] = col;
  }
  if (!isK) return;  // Q-blocks: done (no further LDS phases)

  // ---- Vt from prefetch regs: us2 row-pair stores, conflict-free ----
#pragma unroll
  for (int k = 0; k < 2; k++) {
    int j = tid + k * 512;
    int s0 = (j & 31) * 2;
    int e4 = (j >> 5) * 4;
#pragma unroll
    for (int i = 0; i < 4; i++) {
      us2 w2 = {f2bf(vpa[k][i]), f2bf(vpb[k][i])};
      *(us2*)&Vt[(e4 + i) * 72 + s0] = w2;
    }
  }
  __syncthreads();

  const int b = row0 >> 11;
  const int c = (row0 >> 6) & 31;  // this block's chunk

  // ---- N sums over 64 rows (vectorized: 8x ds_read_b128) ----
  if (tid < 128) {
    float ns = 0.f;
#pragma unroll
    for (int s8 = 0; s8 < 64; s8 += 8) {
      us8 v = *(const us8*)&KdT[tid * 72 + s8];
#pragma unroll
      for (int i = 0; i < 8; i++) ns += bf2f(v[i]);
    }
    N32[(size_t)(b * 32 + c) * 128 + tid] = ns;
  }

  // ---- kv MFMA: KVT[e][d] = sum_{s<64} V[s][e]*phiK[s][d] ----
  {
    const int et = wv;  // 8 e-tiles / 8 waves
    s8v a0 = *(const s8v*)&Vt[(et * 16 + ln) * 72 + q * 8];
    s8v a1 = *(const s8v*)&Vt[(et * 16 + ln) * 72 + 32 + q * 8];
    f4v ac[8];
#pragma unroll
    for (int dt = 0; dt < 8; dt++) ac[dt] = (f4v){0.f, 0.f, 0.f, 0.f};
#pragma unroll
    for (int dt = 0; dt < 8; dt++) {
      s8v b0 = *(const s8v*)&KdT[(dt * 16 + ln) * 72 + q * 8];
      ac[dt] = __builtin_amdgcn_mfma_f32_16x16x32_bf16(a0, b0, ac[dt], 0, 0, 0);
      s8v b1 = *(const s8v*)&KdT[(dt * 16 + ln) * 72 + 32 + q * 8];
      ac[dt] = __builtin_amdgcn_mfma_f32_16x16x32_bf16(a1, b1, ac[dt], 0, 0, 0);
    }
#pragma unroll
    for (int dt = 0; dt < 8; dt++)
#pragma unroll
      for (int r = 0; r < 4; r++) {
        int e = et * 16 + q * 4 + r;
        int d = dt * 16 + ln;
        KVTb[((size_t)(b * 128 + e) * 32 + c) * 128 + d] = f2bf(ac[dt][r]);
      }
  }
}

// ---------------------------------------------------------------------------
// Kernel 1.5: exclusive chunk-prefix scan of KVT and N.  132 blk x 128 thr.
//  blocks 0..127: (b = id>>5, e0 = (id&31)*4).  Stage the 4e x 32c x 128d
//    KVT slice linearly into 32 KB LDS (16 independent coalesced us8 loads
//    per thread -> ONE L2-latency exposure), then thread (e = tid>>5,
//    d4 = tid&31) serial-scans 32 chunks from LDS (ds_read_b64 chain,
//    fp32 accumulate, exclusive write-before-add; numerics identical to
//    the previous serial-global version).
//  blocks 128..131: N32 scan for batch b = id-128, thread d = tid < 128
//    (loads independent of the accumulator -> compiler hoists them all).
// ---------------------------------------------------------------------------
__global__ __launch_bounds__(128) void scan_kernel(
    const u16* __restrict__ KVTb, const float* __restrict__ N32,
    u16* __restrict__ Mpre, float* __restrict__ Npre) {
  __shared__ __align__(16) u16 st[4 * 32 * 128];  // 32 KB
  const int id = blockIdx.x;
  const int tid = threadIdx.x;
  if (id < 128) {
    const int b = id >> 5;
    const int e0 = (id & 31) * 4;
    // ---- stage: linear copy of KVTb[b][e0:e0+4][*][*] (16384 u16) ----
    const u16* src = &KVTb[(size_t)(b * 128 + e0) * 4096];
#pragma unroll
    for (int k = 0; k < 16; k++) {
      int j = (tid + k * 128) * 8;  // us8 index * 8
      *(us8*)&st[j] = *(const us8*)&src[j];
    }
    __syncthreads();
    // ---- scan: thread (e, d4) over 32 chunks from LDS ----
    const int e = tid >> 5;        // 0..3
    const int d4 = (tid & 31) * 4; // 0..124
    float a0 = 0.f, a1 = 0.f, a2 = 0.f, a3 = 0.f;
    u16* dst = &Mpre[((size_t)(b * 32) * 128 + e0 + e) * 128 + d4];
    for (int c = 0; c < 32; c++) {
      us4 w = {f2bf(a0), f2bf(a1), f2bf(a2), f2bf(a3)};
      *(us4*)&dst[(size_t)c * 16384] = w;
      us4 t = *(const us4*)&st[(e * 32 + c) * 128 + d4];
      a0 += bf2f(t[0]);
      a1 += bf2f(t[1]);
      a2 += bf2f(t[2]);
      a3 += bf2f(t[3]);
    }
  } else if (tid < 128) {
    const int b = id - 128;
    const float* src = &N32[(size_t)b * 4096 + tid];
    float* dst = &Npre[(size_t)b * 4096 + tid];
    float a = 0.f;
    for (int cc = 0; cc < 32; cc++) {
      dst[cc * 128] = a;
      a += src[cc * 128];
    }
  }
}

// ---------------------------------------------------------------------------
// Kernel 2: outputs (byte-identical to the R2 91.6us version).  Block id =
// c*16 + (b*4+h): same-(b,h) blocks differ by 16 (≡0 mod 8) -> same XCD
// under round-robin placement.  256 thr = 4 waves.  Grid 512, 2 blk/CU.
// ---------------------------------------------------------------------------
__global__ __launch_bounds__(256) void out_kernel(
    const u16* __restrict__ phiKb, const u16* __restrict__ phiQb,
    const float* __restrict__ V, const u16* __restrict__ Mpre,
    const float* __restrict__ Npre, float* __restrict__ out) {
  __shared__ __align__(16) u16 Qs[64 * 136];  // [t][d]
  __shared__ __align__(16) u16 Ks[64 * 136];  // [s][d]
  __shared__ __align__(16) u16 Ms[32 * 136];  // M^T prefix rows of quarter
  __shared__ __align__(16) u16 Vt[32 * 72];   // [e][s]
  __shared__ __align__(16) u16 Ps[64 * 72];   // [t][s], masked
  __shared__ float Ns[128];
  __shared__ float rs[64];

  const int tid = threadIdx.x;
  const int id = blockIdx.x;
  const int c = id >> 4;         // chunk 0..31
  const int g = id & 15;         // (b,h) group -> XCD-stable
  const int b = g >> 2;
  const int h = g & 3;
  const int srow0 = b * 2048 + c * 64;
  const int ecol0 = h * 32;
  const int wv = tid >> 6;
  const int lane = tid & 63;
  const int q = lane >> 4;
  const int ln = lane & 15;

  // ---- V prefetch (row-pairs of this 32-col quarter) ----
  const int vs0 = (tid & 31) * 2;
  const int ve4 = (tid >> 5) * 4;  // 0..28
  v4 va = *(const v4*)&V[(size_t)(srow0 + vs0) * 128 + ecol0 + ve4];
  v4 vb = *(const v4*)&V[(size_t)(srow0 + vs0 + 1) * 128 + ecol0 + ve4];

  // ---- stage Qs, Ks (64 x 128 bf16 each) ----
#pragma unroll
  for (int k = 0; k < 4; k++) {
    int j = tid + k * 256;  // 0..1023
    int t = j >> 4;
    int d8 = (j & 15) * 8;
    *(us8*)&Qs[t * 136 + d8] = *(const us8*)&phiQb[(size_t)(srow0 + t) * 128 + d8];
    *(us8*)&Ks[t * 136 + d8] = *(const us8*)&phiKb[(size_t)(srow0 + t) * 128 + d8];
  }

  // ---- exclusive M-prefix: precomputed, 2 coalesced us8 loads ----
  {
    const int se = tid >> 4;          // 0..15
    const int sd8 = (tid & 15) * 8;
    const u16* mp = &Mpre[((size_t)(b * 32 + c) * 128 + ecol0) * 128 + sd8];
    *(us8*)&Ms[se * 136 + sd8] = *(const us8*)&mp[se * 128];
    *(us8*)&Ms[(16 + se) * 136 + sd8] = *(const us8*)&mp[(16 + se) * 128];
  }
  // ---- exclusive N-prefix: precomputed ----
  if (tid < 128) Ns[tid] = Npre[(size_t)(b * 32 + c) * 128 + tid];
  // ---- Vt: us2 row-pair stores, conflict-free ----
#pragma unroll
  for (int i = 0; i < 4; i++) {
    us2 w2 = {f2bf(va[i]), f2bf(vb[i])};
    *(us2*)&Vt[(ve4 + i) * 72 + vs0] = w2;
  }
  __syncthreads();

  // ---- P = Q.K^T (wave = row-tile tr=wv; tc 0..3, causal) ----
  {
    const int tr = wv;
    for (int tc = 0; tc < 4; tc++) {  // wave-uniform bound
      f4v acc = {0.f, 0.f, 0.f, 0.f};
      if (tc <= tr) {
#pragma unroll
        for (int ks = 0; ks < 4; ks++) {
          s8v a = *(const s8v*)&Qs[(tr * 16 + ln) * 136 + ks * 32 + q * 8];
          s8v bb = *(const s8v*)&Ks[(tc * 16 + ln) * 136 + ks * 32 + q * 8];
          acc = __builtin_amdgcn_mfma_f32_16x16x32_bf16(a, bb, acc, 0, 0, 0);
        }
      }
      const int s_g = tc * 16 + ln;
#pragma unroll
      for (int r = 0; r < 4; r++) {
        int t_g = tr * 16 + q * 4 + r;
        Ps[t_g * 72 + s_g] = f2bf(s_g <= t_g ? acc[r] : 0.f);
      }
    }
  }
  __syncthreads();

  // ---- denominators: rs[t] = rowsum(P) + Q[t,:].Ns  (us8-vectorized) ----
  {
    const int t = tid >> 2;
    const int p4 = tid & 3;
    float rsl = 0.f;
    us8 pa = *(const us8*)&Ps[t * 72 + p4 * 16];
    us8 pb = *(const us8*)&Ps[t * 72 + p4 * 16 + 8];
#pragma unroll
    for (int i = 0; i < 8; i++) rsl += bf2f(pa[i]) + bf2f(pb[i]);
#pragma unroll
    for (int kk = 0; kk < 4; kk++) {
      us8 qv = *(const us8*)&Qs[t * 136 + p4 * 32 + kk * 8];
#pragma unroll
      for (int i = 0; i < 8; i++)
        rsl += bf2f(qv[i]) * Ns[p4 * 32 + kk * 8 + i];
    }
    rsl += __shfl_down(rsl, 2, 4);
    rsl += __shfl_down(rsl, 1, 4);
    if (p4 == 0) rs[t] = rsl;
  }

  // ---- out = P@V + Q@M (wave: et = wv&1; tr in {wv>>1, wv>>1 + 2}) ----
  const int et = wv & 1;
  f4v acc2[2];
#pragma unroll
  for (int i = 0; i < 2; i++) acc2[i] = (f4v){0.f, 0.f, 0.f, 0.f};
#pragma unroll
  for (int i = 0; i < 2; i++) {
    const int tr2 = (wv >> 1) + 2 * i;
#pragma unroll
    for (int ks2 = 0; ks2 < 2; ks2++) {
      s8v a_p = *(const s8v*)&Ps[(tr2 * 16 + ln) * 72 + ks2 * 32 + q * 8];
      s8v b_v = *(const s8v*)&Vt[(et * 16 + ln) * 72 + ks2 * 32 + q * 8];
      acc2[i] = __builtin_amdgcn_mfma_f32_16x16x32_bf16(a_p, b_v, acc2[i], 0, 0, 0);
    }
#pragma unroll
    for (int ks = 0; ks < 4; ks++) {
      s8v a_q = *(const s8v*)&Qs[(tr2 * 16 + ln) * 136 + ks * 32 + q * 8];
      s8v b_m = *(const s8v*)&Ms[(et * 16 + ln) * 136 + ks * 32 + q * 8];
      acc2[i] = __builtin_amdgcn_mfma_f32_16x16x32_bf16(a_q, b_m, acc2[i], 0, 0, 0);
    }
  }
  __syncthreads();  // rs ready

  // ---- epilogue ----
#pragma unroll
  for (int i = 0; i < 2; i++) {
    const int tr2 = (wv >> 1) + 2 * i;
#pragma unroll
    for (int r = 0; r < 4; r++) {
      int t_g = tr2 * 16 + q * 4 + r;
      float rv = rs[t_g];
      float den = rv + (rv > 0.f ? 1e-6f : (rv < 0.f ? -1e-6f : 0.f));
      out[(size_t)(srow0 + t_g) * 128 + ecol0 + et * 16 + ln] =
          acc2[i][r] / den;
    }
  }
}

// ---------------------------------------------------------------------------
extern "C" void kernel_launch(void* const* d_in, const int* in_sizes, int n_in,
                              void* d_out, int out_size, void* d_ws,
                              size_t ws_size, hipStream_t stream) {
  (void)in_sizes; (void)n_in; (void)out_size; (void)ws_size;
  const float* K = (const float*)d_in[0];
  const float* Q = (const float*)d_in[1];
  const float* V = (const float*)d_in[2];
  const float* W = (const float*)d_in[6];
  float* out = (float*)d_out;
  float* ws = (float*)d_ws;

  u16* phiKb = (u16*)(ws + OFF_PHIKB);
  u16* phiQb = (u16*)(ws + OFF_PHIQB);
  u16* KVTb = (u16*)(ws + OFF_KVTB);
  float* N32 = ws + OFF_N32;
  u16* Mpre = (u16*)(ws + OFF_MPRE);
  float* Npre = ws + OFF_NPRE;

  phikv_kernel<<<dim3(128, 2), 512, 0, stream>>>(K, Q, V, W, phiKb, phiQb,
                                                 KVTb, N32);
  scan_kernel<<<132, 128, 0, stream>>>(KVTb, N32, Mpre, Npre);
  out_kernel<<<512, 256, 0, stream>>>(phiKb, phiQb, V, Mpre, Npre, out);
}

// Round 6
// 90.627 us; speedup vs baseline: 1.0198x; 1.0062x over previous
//
#include <hip/hip_runtime.h>

// Performer causal linear attention — 3-dispatch bf16-MFMA pipeline, L=64.
// B=4, S=2048, D=128; chunks of L=64 (128 chunks, 32/batch).
//  phikv (256 blk x 512 thr): phi = scale*exp(W@x) via MFMA; phi stored to
//         global DIRECTLY from acc regs; K-blocks also emit per-chunk
//         KVT[e][d] (bf16, [b][e][c][d]) + N[d] (fp32).
//  scan  (132 blk x 128 thr): exclusive chunk-prefix of KVT -> Mpre
//         (bf16, fp32-accumulated) and N32 -> Npre (fp32); 32-KB LDS stage.
//  out (512 blk x 256 thr, 2 blk/CU): R2 wave layout, but denominators are
//         computed IN-REGISTER during QK^T (fp32 acc, masked; + Q.Ns with
//         pre-barrier Ns) and Q@M MFMAs hoisted pre-barrier -> post-Ps-
//         barrier tail is only 4 P@V MFMAs + epilogue.
// (R5: grid barriers ~100us.  R10: scan dispatch -4.3us.  R11: shaves
//  -1.4us -> 91.6.  R12/R13: out wave-layout changes regressed; reverted.
//  R14: LDS-staged scan -> 91.2.  This round: shrink out's barrier tail.)
typedef float v4 __attribute__((ext_vector_type(4)));
typedef short s8v __attribute__((ext_vector_type(8)));   // bf16x8 fragment
typedef float f4v __attribute__((ext_vector_type(4)));   // mfma C/D
typedef unsigned short u16;
typedef u16 us2 __attribute__((ext_vector_type(2)));
typedef u16 us4 __attribute__((ext_vector_type(4)));
typedef u16 us8 __attribute__((ext_vector_type(8)));

// workspace layout (float units)
#define OFF_PHIKB 0            // bf16 [8192][128]          (524288 f)
#define OFF_PHIQB 524288       // bf16 [8192][128]          (524288 f)
#define OFF_KVTB  1048576      // bf16 [4][128][32][128]    (1048576 f)
#define OFF_N32   2097152      // fp32 [4][32][128]         (16384 f)
#define OFF_MPRE  2113536      // bf16 [4][32][128][128]    (1048576 f)
#define OFF_NPRE  3162112      // fp32 [4][32][128]         (16384 f)
// total 3178496 floats = 12.7 MB

__device__ inline u16 f2bf(float f) {
  union { float f; unsigned u; } v; v.f = f;
  unsigned r = v.u + 0x7fffu + ((v.u >> 16) & 1u);
  return (u16)(r >> 16);
}
__device__ inline float bf2f(u16 h) {
  union { unsigned u; float f; } v; v.u = ((unsigned)h) << 16; return v.f;
}

// ---------------------------------------------------------------------------
// Kernel 1: fused phi (+ per-chunk KV/N for the K tensor).  L=64 chunk/block.
// Grid (128, 2): x = 64-row slab (=1 chunk), y = 0:K(+kv) / 1:Q.  512 thr.
// (byte-identical to R14's verified version)
// ---------------------------------------------------------------------------
__global__ __launch_bounds__(512) void phikv_kernel(
    const float* __restrict__ K, const float* __restrict__ Q,
    const float* __restrict__ V, const float* __restrict__ W,
    u16* __restrict__ phiKb, u16* __restrict__ phiQb,
    u16* __restrict__ KVTb, float* __restrict__ N32) {
  __shared__ __align__(16) u16 smem[26112];
  __shared__ float srowsq[64];
  __shared__ float scl[64];
  u16* Xb = smem;
  u16* Wb = smem + 8704;
  u16* KdT = smem;          // phase B
  u16* Vt = smem + 9216;    // phase B

  const int tid = threadIdx.x;
  const bool isK = (blockIdx.y == 0);
  const float* X = isK ? K : Q;
  u16* outPhi = isK ? phiKb : phiQb;
  const int row0 = blockIdx.x * 64;
  const int wv = tid >> 6;   // 0..7
  const int lane = tid & 63;
  const int q = lane >> 4;
  const int ln = lane & 15;

  // ---- prefetch V row-pairs (K-blocks): enables conflict-free transpose ----
  v4 vpa[2], vpb[2];
  if (isK) {
#pragma unroll
    for (int k = 0; k < 2; k++) {
      int j = tid + k * 512;
      int s0 = (j & 31) * 2;
      int e4 = (j >> 5) * 4;  // 0..124
      vpa[k] = *(const v4*)&V[(size_t)(row0 + s0) * 128 + e4];
      vpb[k] = *(const v4*)&V[(size_t)(row0 + s0 + 1) * 128 + e4];
    }
  }

  // ---- stage X -> bf16 Xb + per-row sumsq (fp32, shuffle-reduced) ----
#pragma unroll
  for (int k = 0; k < 4; k++) {
    int j = tid + k * 512;
    int r = j >> 5;
    int c4 = (j & 31) * 4;
    v4 x = *(const v4*)&X[(size_t)(row0 + r) * 128 + c4];
    us4 xb;
    float p = 0.f;
#pragma unroll
    for (int i = 0; i < 4; i++) { xb[i] = f2bf(x[i]); p += x[i] * x[i]; }
    *(us4*)&Xb[r * 136 + c4] = xb;
    p += __shfl_down(p, 16, 32);
    p += __shfl_down(p, 8, 32);
    p += __shfl_down(p, 4, 32);
    p += __shfl_down(p, 2, 32);
    p += __shfl_down(p, 1, 32);
    if ((tid & 31) == 0) srowsq[r] = p;
  }
  // ---- stage W -> bf16 Wb ----
#pragma unroll
  for (int k = 0; k < 8; k++) {
    int j = tid + k * 512;
    int r = j >> 5;
    int c4 = (j & 31) * 4;
    v4 w = *(const v4*)&W[(size_t)r * 128 + c4];
    us4 wb;
#pragma unroll
    for (int i = 0; i < 4; i++) wb[i] = f2bf(w[i]);
    *(us4*)&Wb[r * 136 + c4] = wb;
  }
  __syncthreads();
  if (tid < 64)
    scl[tid] = 0.08838834764831845f * __expf(-0.5f * sqrtf(srowsq[tid]));

  // ---- phi MFMA: wave -> row-tile tr=wv>>1, col-tiles (wv&1)*4.. ----
  const int tr = wv >> 1;
  const int cb = (wv & 1) * 4;
  f4v acc[4];
#pragma unroll
  for (int i = 0; i < 4; i++) acc[i] = (f4v){0.f, 0.f, 0.f, 0.f};
#pragma unroll
  for (int ks = 0; ks < 4; ks++) {
    s8v a = *(const s8v*)&Xb[(tr * 16 + ln) * 136 + ks * 32 + q * 8];
#pragma unroll
    for (int i = 0; i < 4; i++) {
      s8v bb = *(const s8v*)&Wb[((cb + i) * 16 + ln) * 136 + ks * 32 + q * 8];
      acc[i] = __builtin_amdgcn_mfma_f32_16x16x32_bf16(a, bb, acc[i], 0, 0, 0);
    }
  }
  __syncthreads();  // Xb/Wb reads done (phase-B aliasing safe); scl ready

  // ---- epilogue: phi -> global direct + KdT (transposed, K-blocks) ----
#pragma unroll
  for (int i = 0; i < 4; i++) {
    const int ct = cb + i;
    us4 col;
#pragma unroll
    for (int r = 0; r < 4; r++) {
      int row = tr * 16 + q * 4 + r;
      u16 hv = f2bf(scl[row] * __expf(acc[i][r]));
      outPhi[(size_t)(row0 + row) * 128 + ct * 16 + ln] = hv;
      col[r] = hv;
    }
    if (isK) *(us4*)&KdT[(ct * 16 + ln) * 72 + tr * 16 + q * 4] = col;
  }
  if (!isK) return;  // Q-blocks: done (no further LDS phases)

  // ---- Vt from prefetch regs: us2 row-pair stores, conflict-free ----
#pragma unroll
  for (int k = 0; k < 2; k++) {
    int j = tid + k * 512;
    int s0 = (j & 31) * 2;
    int e4 = (j >> 5) * 4;
#pragma unroll
    for (int i = 0; i < 4; i++) {
      us2 w2 = {f2bf(vpa[k][i]), f2bf(vpb[k][i])};
      *(us2*)&Vt[(e4 + i) * 72 + s0] = w2;
    }
  }
  __syncthreads();

  const int b = row0 >> 11;
  const int c = (row0 >> 6) & 31;  // this block's chunk

  // ---- N sums over 64 rows (vectorized: 8x ds_read_b128) ----
  if (tid < 128) {
    float ns = 0.f;
#pragma unroll
    for (int s8 = 0; s8 < 64; s8 += 8) {
      us8 v = *(const us8*)&KdT[tid * 72 + s8];
#pragma unroll
      for (int i = 0; i < 8; i++) ns += bf2f(v[i]);
    }
    N32[(size_t)(b * 32 + c) * 128 + tid] = ns;
  }

  // ---- kv MFMA: KVT[e][d] = sum_{s<64} V[s][e]*phiK[s][d] ----
  {
    const int et = wv;  // 8 e-tiles / 8 waves
    s8v a0 = *(const s8v*)&Vt[(et * 16 + ln) * 72 + q * 8];
    s8v a1 = *(const s8v*)&Vt[(et * 16 + ln) * 72 + 32 + q * 8];
    f4v ac[8];
#pragma unroll
    for (int dt = 0; dt < 8; dt++) ac[dt] = (f4v){0.f, 0.f, 0.f, 0.f};
#pragma unroll
    for (int dt = 0; dt < 8; dt++) {
      s8v b0 = *(const s8v*)&KdT[(dt * 16 + ln) * 72 + q * 8];
      ac[dt] = __builtin_amdgcn_mfma_f32_16x16x32_bf16(a0, b0, ac[dt], 0, 0, 0);
      s8v b1 = *(const s8v*)&KdT[(dt * 16 + ln) * 72 + 32 + q * 8];
      ac[dt] = __builtin_amdgcn_mfma_f32_16x16x32_bf16(a1, b1, ac[dt], 0, 0, 0);
    }
#pragma unroll
    for (int dt = 0; dt < 8; dt++)
#pragma unroll
      for (int r = 0; r < 4; r++) {
        int e = et * 16 + q * 4 + r;
        int d = dt * 16 + ln;
        KVTb[((size_t)(b * 128 + e) * 32 + c) * 128 + d] = f2bf(ac[dt][r]);
      }
  }
}

// ---------------------------------------------------------------------------
// Kernel 1.5: exclusive chunk-prefix scan of KVT and N.  132 blk x 128 thr.
// (byte-identical to R14's verified version)
// ---------------------------------------------------------------------------
__global__ __launch_bounds__(128) void scan_kernel(
    const u16* __restrict__ KVTb, const float* __restrict__ N32,
    u16* __restrict__ Mpre, float* __restrict__ Npre) {
  __shared__ __align__(16) u16 st[4 * 32 * 128];  // 32 KB
  const int id = blockIdx.x;
  const int tid = threadIdx.x;
  if (id < 128) {
    const int b = id >> 5;
    const int e0 = (id & 31) * 4;
    // ---- stage: linear copy of KVTb[b][e0:e0+4][*][*] (16384 u16) ----
    const u16* src = &KVTb[(size_t)(b * 128 + e0) * 4096];
#pragma unroll
    for (int k = 0; k < 16; k++) {
      int j = (tid + k * 128) * 8;  // us8 index * 8
      *(us8*)&st[j] = *(const us8*)&src[j];
    }
    __syncthreads();
    // ---- scan: thread (e, d4) over 32 chunks from LDS ----
    const int e = tid >> 5;        // 0..3
    const int d4 = (tid & 31) * 4; // 0..124
    float a0 = 0.f, a1 = 0.f, a2 = 0.f, a3 = 0.f;
    u16* dst = &Mpre[((size_t)(b * 32) * 128 + e0 + e) * 128 + d4];
    for (int c = 0; c < 32; c++) {
      us4 w = {f2bf(a0), f2bf(a1), f2bf(a2), f2bf(a3)};
      *(us4*)&dst[(size_t)c * 16384] = w;
      us4 t = *(const us4*)&st[(e * 32 + c) * 128 + d4];
      a0 += bf2f(t[0]);
      a1 += bf2f(t[1]);
      a2 += bf2f(t[2]);
      a3 += bf2f(t[3]);
    }
  } else if (tid < 128) {
    const int b = id - 128;
    const float* src = &N32[(size_t)b * 4096 + tid];
    float* dst = &Npre[(size_t)b * 4096 + tid];
    float a = 0.f;
    for (int cc = 0; cc < 32; cc++) {
      dst[cc * 128] = a;
      a += src[cc * 128];
    }
  }
}

// ---------------------------------------------------------------------------
// Kernel 2: outputs.  Block id = c*16 + (b*4+h) (XCD-stable).  256 thr =
// 4 waves (R2 layout).  Denominators in-register during QK^T (fp32 masked
// acc + Q.Ns, 16-lane xor-reduce, rs[] written pre-barrier); Q@M hoisted
// pre-barrier.  Post-barrier tail: 4 P@V MFMAs + epilogue only.
// Grid 512, 2 blk/CU.
// ---------------------------------------------------------------------------
__global__ __launch_bounds__(256) void out_kernel(
    const u16* __restrict__ phiKb, const u16* __restrict__ phiQb,
    const float* __restrict__ V, const u16* __restrict__ Mpre,
    const float* __restrict__ Npre, float* __restrict__ out) {
  __shared__ __align__(16) u16 Qs[64 * 136];  // [t][d]
  __shared__ __align__(16) u16 Ks[64 * 136];  // [s][d]
  __shared__ __align__(16) u16 Ms[32 * 136];  // M^T prefix rows of quarter
  __shared__ __align__(16) u16 Vt[32 * 72];   // [e][s]
  __shared__ __align__(16) u16 Ps[64 * 72];   // [t][s], masked
  __shared__ float Ns[128];
  __shared__ float rs[64];

  const int tid = threadIdx.x;
  const int id = blockIdx.x;
  const int c = id >> 4;         // chunk 0..31
  const int g = id & 15;         // (b,h) group -> XCD-stable
  const int b = g >> 2;
  const int h = g & 3;
  const int srow0 = b * 2048 + c * 64;
  const int ecol0 = h * 32;
  const int wv = tid >> 6;
  const int lane = tid & 63;
  const int q = lane >> 4;
  const int ln = lane & 15;

  // ---- V prefetch (row-pairs of this 32-col quarter) ----
  const int vs0 = (tid & 31) * 2;
  const int ve4 = (tid >> 5) * 4;  // 0..28
  v4 va = *(const v4*)&V[(size_t)(srow0 + vs0) * 128 + ecol0 + ve4];
  v4 vb = *(const v4*)&V[(size_t)(srow0 + vs0 + 1) * 128 + ecol0 + ve4];

  // ---- stage Qs, Ks (64 x 128 bf16 each) ----
#pragma unroll
  for (int k = 0; k < 4; k++) {
    int j = tid + k * 256;  // 0..1023
    int t = j >> 4;
    int d8 = (j & 15) * 8;
    *(us8*)&Qs[t * 136 + d8] = *(const us8*)&phiQb[(size_t)(srow0 + t) * 128 + d8];
    *(us8*)&Ks[t * 136 + d8] = *(const us8*)&phiKb[(size_t)(srow0 + t) * 128 + d8];
  }

  // ---- exclusive M-prefix: precomputed, 2 coalesced us8 loads ----
  {
    const int se = tid >> 4;          // 0..15
    const int sd8 = (tid & 15) * 8;
    const u16* mp = &Mpre[((size_t)(b * 32 + c) * 128 + ecol0) * 128 + sd8];
    *(us8*)&Ms[se * 136 + sd8] = *(const us8*)&mp[se * 128];
    *(us8*)&Ms[(16 + se) * 136 + sd8] = *(const us8*)&mp[(16 + se) * 128];
  }
  // ---- exclusive N-prefix: precomputed ----
  if (tid < 128) Ns[tid] = Npre[(size_t)(b * 32 + c) * 128 + tid];
  // ---- Vt: us2 row-pair stores, conflict-free ----
#pragma unroll
  for (int i = 0; i < 4; i++) {
    us2 w2 = {f2bf(va[i]), f2bf(vb[i])};
    *(us2*)&Vt[(ve4 + i) * 72 + vs0] = w2;
  }
  __syncthreads();

  // ---- P = Q.K^T (wave = row-tile tr=wv) with in-register denominators ----
  float dsum[4] = {0.f, 0.f, 0.f, 0.f};  // masked fp32 P-rowsum partials
  {
    const int tr = wv;
    for (int tc = 0; tc < 4; tc++) {  // wave-uniform bound
      f4v acc = {0.f, 0.f, 0.f, 0.f};
      if (tc <= tr) {
#pragma unroll
        for (int ks = 0; ks < 4; ks++) {
          s8v a = *(const s8v*)&Qs[(tr * 16 + ln) * 136 + ks * 32 + q * 8];
          s8v bb = *(const s8v*)&Ks[(tc * 16 + ln) * 136 + ks * 32 + q * 8];
          acc = __builtin_amdgcn_mfma_f32_16x16x32_bf16(a, bb, acc, 0, 0, 0);
        }
      }
      const int s_g = tc * 16 + ln;
#pragma unroll
      for (int r = 0; r < 4; r++) {
        int t_g = tr * 16 + q * 4 + r;
        float pv = (s_g <= t_g) ? acc[r] : 0.f;
        Ps[t_g * 72 + s_g] = f2bf(pv);
        dsum[r] += pv;
      }
    }
    // Q.Ns partial: lane ln covers d = ln*8 .. ln*8+7 for its 4 rows
    v4 n0 = *(const v4*)&Ns[ln * 8];
    v4 n1 = *(const v4*)&Ns[ln * 8 + 4];
#pragma unroll
    for (int r = 0; r < 4; r++) {
      int t_g = tr * 16 + q * 4 + r;
      us8 qv = *(const us8*)&Qs[t_g * 136 + ln * 8];
      float s = 0.f;
#pragma unroll
      for (int i = 0; i < 4; i++) s += bf2f(qv[i]) * n0[i];
#pragma unroll
      for (int i = 0; i < 4; i++) s += bf2f(qv[4 + i]) * n1[i];
      dsum[r] += s;
    }
    // xor-reduce over the 16-lane column group
#pragma unroll
    for (int r = 0; r < 4; r++) {
      dsum[r] += __shfl_xor(dsum[r], 1, 16);
      dsum[r] += __shfl_xor(dsum[r], 2, 16);
      dsum[r] += __shfl_xor(dsum[r], 4, 16);
      dsum[r] += __shfl_xor(dsum[r], 8, 16);
    }
    if (ln == 0) {
#pragma unroll
      for (int r = 0; r < 4; r++) rs[tr * 16 + q * 4 + r] = dsum[r];
    }
  }

  // ---- Q@M MFMAs hoisted pre-barrier (depend only on Qs/Ms) ----
  const int et = wv & 1;
  f4v acc2[2];
#pragma unroll
  for (int i = 0; i < 2; i++) {
    acc2[i] = (f4v){0.f, 0.f, 0.f, 0.f};
    const int tr2 = (wv >> 1) + 2 * i;
#pragma unroll
    for (int ks = 0; ks < 4; ks++) {
      s8v a_q = *(const s8v*)&Qs[(tr2 * 16 + ln) * 136 + ks * 32 + q * 8];
      s8v b_m = *(const s8v*)&Ms[(et * 16 + ln) * 136 + ks * 32 + q * 8];
      acc2[i] = __builtin_amdgcn_mfma_f32_16x16x32_bf16(a_q, b_m, acc2[i], 0, 0, 0);
    }
  }
  __syncthreads();  // Ps + rs ready

  // ---- post-barrier tail: P@V only ----
#pragma unroll
  for (int i = 0; i < 2; i++) {
    const int tr2 = (wv >> 1) + 2 * i;
#pragma unroll
    for (int ks2 = 0; ks2 < 2; ks2++) {
      s8v a_p = *(const s8v*)&Ps[(tr2 * 16 + ln) * 72 + ks2 * 32 + q * 8];
      s8v b_v = *(const s8v*)&Vt[(et * 16 + ln) * 72 + ks2 * 32 + q * 8];
      acc2[i] = __builtin_amdgcn_mfma_f32_16x16x32_bf16(a_p, b_v, acc2[i], 0, 0, 0);
    }
  }

  // ---- epilogue ----
#pragma unroll
  for (int i = 0; i < 2; i++) {
    const int tr2 = (wv >> 1) + 2 * i;
#pragma unroll
    for (int r = 0; r < 4; r++) {
      int t_g = tr2 * 16 + q * 4 + r;
      float rv = rs[t_g];
      float den = rv + (rv > 0.f ? 1e-6f : (rv < 0.f ? -1e-6f : 0.f));
      out[(size_t)(srow0 + t_g) * 128 + ecol0 + et * 16 + ln] =
          acc2[i][r] / den;
    }
  }
}

// ---------------------------------------------------------------------------
extern "C" void kernel_launch(void* const* d_in, const int* in_sizes, int n_in,
                              void* d_out, int out_size, void* d_ws,
                              size_t ws_size, hipStream_t stream) {
  (void)in_sizes; (void)n_in; (void)out_size; (void)ws_size;
  const float* K = (const float*)d_in[0];
  const float* Q = (const float*)d_in[1];
  const float* V = (const float*)d_in[2];
  const float* W = (const float*)d_in[6];
  float* out = (float*)d_out;
  float* ws = (float*)d_ws;

  u16* phiKb = (u16*)(ws + OFF_PHIKB);
  u16* phiQb = (u16*)(ws + OFF_PHIQB);
  u16* KVTb = (u16*)(ws + OFF_KVTB);
  float* N32 = ws + OFF_N32;
  u16* Mpre = (u16*)(ws + OFF_MPRE);
  float* Npre = ws + OFF_NPRE;

  phikv_kernel<<<dim3(128, 2), 512, 0, stream>>>(K, Q, V, W, phiKb, phiQb,
                                                 KVTb, N32);
  scan_kernel<<<132, 128, 0, stream>>>(KVTb, N32, Mpre, Npre);
  out_kernel<<<512, 256, 0, stream>>>(phiKb, phiQb, V, Mpre, Npre, out);
}